// Round 1
// baseline (1703.231 us; speedup 1.0000x reference)
//
#include <hip/hip_runtime.h>
#include <cstddef>

#define PI_F 3.14159265358979323846f

#define NCH    256   // C
#define NBATCH 32    // B
#define NSP    32    // n
#define NFJ    17    // n/2+1
#define NFREQ  544   // n * (n/2+1)
#define NCHUNK 4
#define FPC    136   // freqs per chunk

// workspace layout (bytes)
#define SZ_AT   ((size_t)FPC*NCH*NCH*8)          // 71,303,168
#define SZ_Z    ((size_t)NFREQ*NCH*NBATCH*8)     // 35,651,584
#define OFF_AT  ((size_t)0)
#define OFF_Z0  (OFF_AT + SZ_AT)                 // z0; later aliased as wxh
#define OFF_WX  (OFF_Z0 + SZ_Z)
#define OFF_TA  (OFF_WX + SZ_Z)                  // tA; also tmp (pre-chunk) and G (post-chunk)
#define OFF_TB  (OFF_TA + SZ_Z)
#define OFF_HT  (OFF_TB + SZ_Z)
#define SZ_HT   ((size_t)NCH*NCH*4)
#define OFF_RED (OFF_HT + SZ_HT)
#define WS_NEED (OFF_RED + (size_t)4096)

__device__ __forceinline__ float2 cmul(float2 a, float2 b) {
    return make_float2(a.x*b.x - a.y*b.y, a.x*b.y + a.y*b.x);
}
// a * conj(b)
__device__ __forceinline__ float2 cmulc(float2 a, float2 b) {
    return make_float2(a.x*b.x + a.y*b.y, a.y*b.x - a.x*b.y);
}

// ---------------- norm of wfft (closed form via Parseval) ----------------
// stored-grid sum over (i<32, j<17) of |FFT2(w_cc')|^2
//   = 512*sum(w^2) + 16*(sum_u a_u^2 + sum_u b_u^2),
//   a_u = sum_v w[u,v],  b_u = sum_v (-1)^v w[u,v]
__global__ void norm_part(const float* __restrict__ w, float* __restrict__ red) {
    int idx = blockIdx.x * 256 + threadIdx.x;     // (c*256+cp)
    const float* wp = w + (size_t)idx * 9;
    float s2 = 0.f, aa = 0.f, bb = 0.f;
#pragma unroll
    for (int u = 0; u < 3; u++) {
        float w0 = wp[u*3+0], w1 = wp[u*3+1], w2 = wp[u*3+2];
        s2 += w0*w0 + w1*w1 + w2*w2;
        float au = w0 + w1 + w2, bu = w0 - w1 + w2;
        aa += au*au; bb += bu*bu;
    }
    float p = 512.f*s2 + 16.f*(aa + bb);
    __shared__ float sm[256];
    sm[threadIdx.x] = p; __syncthreads();
    for (int s = 128; s > 0; s >>= 1) {
        if (threadIdx.x < s) sm[threadIdx.x] += sm[threadIdx.x + s];
        __syncthreads();
    }
    if (threadIdx.x == 0) red[blockIdx.x] = sm[0];
}

__global__ void norm_final(const float* __restrict__ red, const float* __restrict__ alpha,
                           float* __restrict__ sig) {
    __shared__ float sm[256];
    sm[threadIdx.x] = red[threadIdx.x]; __syncthreads();
    for (int s = 128; s > 0; s >>= 1) {
        if (threadIdx.x < s) sm[threadIdx.x] += sm[threadIdx.x + s];
        __syncthreads();
    }
    if (threadIdx.x == 0) sig[0] = alpha[0] / sqrtf(sm[0]);
}

// ---------------- Ht[c][o] = H[o][c] ----------------
__global__ void ht_build(const float* __restrict__ H, float* __restrict__ Ht) {
    Ht[(size_t)threadIdx.x * NCH + blockIdx.x] = H[(size_t)blockIdx.x * NCH + threadIdx.x];
}

// ---------------- rfft2 per (c,b) tile -> tmp[cb][f] ----------------
__global__ void rfft2_tile(const float* __restrict__ x, float2* __restrict__ tmp) {
    int c = blockIdx.x >> 5, b = blockIdx.x & 31;
    __shared__ float  xt[1024];
    __shared__ float2 T[544];          // [r*17+j]
    __shared__ float2 wtab[32];        // e^{-i 2pi m/32}
    int t = threadIdx.x;
    const float* xp = x + ((size_t)(b * NCH + c)) * 1024;   // x[b][c][r][s]
    for (int m = t; m < 1024; m += 64) xt[m] = xp[m];
    if (t < 32) {
        float ph = -2.f * PI_F * (float)t / 32.f;
        wtab[t] = make_float2(cosf(ph), sinf(ph));
    }
    __syncthreads();
    // step 1: T[r][j] = sum_s x[r,s] w^{(j*s)&31}
    for (int o = t; o < 544; o += 64) {
        int r = o / 17, j = o - r * 17;
        float2 acc = make_float2(0.f, 0.f);
        for (int s = 0; s < 32; s++) {
            float xv = xt[r*32 + s];
            float2 wv = wtab[(j * s) & 31];
            acc.x += xv * wv.x; acc.y += xv * wv.y;
        }
        T[o] = acc;
    }
    __syncthreads();
    // step 2: z[(i,j)] = sum_r w^{(i*r)&31} * T[r][j]
    float2* op = tmp + (size_t)blockIdx.x * 544;   // cb = c*32+b == blockIdx.x
    for (int o = t; o < 544; o += 64) {
        int i = o / 17, j = o - i * 17;
        float2 acc = make_float2(0.f, 0.f);
        for (int r = 0; r < 32; r++) {
            float2 wv = wtab[(i * r) & 31];
            float2 tv = T[r*17 + j];
            acc.x += wv.x*tv.x - wv.y*tv.y;
            acc.y += wv.x*tv.y + wv.y*tv.x;
        }
        op[o] = acc;
    }
}

// ---------------- transpose tmp[cb][f] -> z0[f][cb] ----------------
__global__ void transpose_cb_f(const float2* __restrict__ tmp, float2* __restrict__ z0) {
    __shared__ float2 tile[32][33];
    int cb0 = blockIdx.x * 32, f0 = blockIdx.y * 32;
    int tx = threadIdx.x & 31, ty = threadIdx.x >> 5;   // ty 0..7
#pragma unroll
    for (int k = 0; k < 4; k++) {
        int row = ty + k * 8;
        tile[row][tx] = tmp[(size_t)(cb0 + row) * 544 + f0 + tx];
    }
    __syncthreads();
#pragma unroll
    for (int k = 0; k < 4; k++) {
        int row = ty + k * 8;   // f-local
        z0[(size_t)(f0 + row) * 8192 + cb0 + tx] = tile[tx][row];
    }
}

// ---------------- A-build: At[fl][cp][c] = A[f][c][cp] ----------------
// A = sigma * ( s_f * conj(Wr[c,cp]) - conj(s_f) * Wr[cp,c] ),
// Wr[c,cp] = sum_t w[c,cp,t] e^{-i 2pi (i*u+j*v)/32},  s_f = e^{-i 2pi (i+j)/32}
__global__ __launch_bounds__(256) void a_build(const float* __restrict__ w,
                                               const float* __restrict__ sig,
                                               float2* __restrict__ At, int f0) {
    __shared__ float2 wtab[32];
    if (threadIdx.x < 32) {
        float ph = -2.f * PI_F * (float)threadIdx.x / 32.f;
        wtab[threadIdx.x] = make_float2(cosf(ph), sinf(ph));
    }
    int ct = blockIdx.x & 15, cpt = blockIdx.x >> 4;
    int c  = ct  * 16 + (threadIdx.x & 15);
    int cp = cpt * 16 + (threadIdx.x >> 4);
    float w1[9], w2[9];
    const float* p1 = w + (size_t)(c * NCH + cp) * 9;
    const float* p2 = w + (size_t)(cp * NCH + c) * 9;
#pragma unroll
    for (int t = 0; t < 9; t++) { w1[t] = p1[t]; w2[t] = p2[t]; }
    float s = sig[0];
    __syncthreads();
    for (int fl = 0; fl < FPC; fl++) {
        int f = f0 + fl;
        int i = f / 17, j = f - i * 17;
        int iu1 = i, iu2 = (2 * i) & 31;
        int jv1 = j, jv2 = (2 * j) & 31;
        int iu[3] = {0, iu1, iu2};
        int jv[3] = {0, jv1, jv2};
        float2 Wr1 = make_float2(0.f, 0.f), Wr2 = make_float2(0.f, 0.f);
#pragma unroll
        for (int u = 0; u < 3; u++) {
#pragma unroll
            for (int v = 0; v < 3; v++) {
                float2 e = wtab[(iu[u] + jv[v]) & 31];
                float a1 = w1[u*3+v], a2 = w2[u*3+v];
                Wr1.x += a1 * e.x; Wr1.y += a1 * e.y;
                Wr2.x += a2 * e.x; Wr2.y += a2 * e.y;
            }
        }
        float2 sf = wtab[(i + j) & 31];
        float2 t1 = cmulc(sf, Wr1);   // sf * conj(Wr1)
        float2 t2 = make_float2(sf.x*Wr2.x + sf.y*Wr2.y,   // conj(sf) * Wr2
                                sf.x*Wr2.y - sf.y*Wr2.x);
        At[((size_t)fl * NCH + cp) * NCH + c] =
            make_float2(s * (t1.x - t2.x), s * (t1.y - t2.y));
    }
}

// ---------------- Neumann term: t_out[f,c,b] = sum_cp A[f,c,cp] t_in[f,cp,b] ----------------
// MODE 0: tout = acc, wx = z0 - 2 acc   (z0 staged in LDS)
// MODE 1: tout = acc, wx += 2 acc
// MODE 2: wx -= 2 acc (no tout)
template<int MODE>
__global__ __launch_bounds__(256) void neumann_k(const float2* __restrict__ At,
                                                 const float2* __restrict__ tin,
                                                 float2* __restrict__ tout,
                                                 float2* __restrict__ wx, int f0) {
    __shared__ float2 zs[NCH * NBATCH];   // 64 KB
    int fl = blockIdx.x >> 2, cq = blockIdx.x & 3;
    int f = f0 + fl;
    const float2* zin = tin + (size_t)f * (NCH * NBATCH);
    for (int m = threadIdx.x; m < NCH * NBATCH; m += 256) zs[m] = zin[m];
    __syncthreads();
    int ci = threadIdx.x & 31, bi = threadIdx.x >> 5;
    int c0 = cq * 64 + ci * 2;
    int b0 = bi * 4;
    const float4* Ap = (const float4*)(At + (size_t)fl * NCH * NCH);
    const float4* zp = (const float4*)zs;
    float2 acc0[4], acc1[4];
#pragma unroll
    for (int k = 0; k < 4; k++) { acc0[k] = make_float2(0,0); acc1[k] = make_float2(0,0); }
    int aidx = cq * 32 + ci;
#pragma unroll 4
    for (int cp = 0; cp < 256; cp++) {
        float4 av = Ap[cp * 128 + aidx];
        float2 a0 = make_float2(av.x, av.y);
        float2 a1 = make_float2(av.z, av.w);
        int zb = (cp * 32 + b0) >> 1;
        float4 zva = zp[zb], zvb = zp[zb + 1];
        float2 zv[4] = { make_float2(zva.x, zva.y), make_float2(zva.z, zva.w),
                         make_float2(zvb.x, zvb.y), make_float2(zvb.z, zvb.w) };
#pragma unroll
        for (int k = 0; k < 4; k++) {
            float2 z = zv[k];
            acc0[k].x += a0.x*z.x - a0.y*z.y; acc0[k].y += a0.x*z.y + a0.y*z.x;
            acc1[k].x += a1.x*z.x - a1.y*z.y; acc1[k].y += a1.x*z.y + a1.y*z.x;
        }
    }
    size_t base = ((size_t)f * NCH + c0) * NBATCH + b0;
#pragma unroll
    for (int k = 0; k < 4; k++) {
        float2 v0 = acc0[k], v1 = acc1[k];
        size_t i0 = base + k, i1 = base + NBATCH + k;
        if (MODE == 0) {
            tout[i0] = v0; tout[i1] = v1;
            float2 s0 = zs[c0 * NBATCH + b0 + k], s1 = zs[(c0 + 1) * NBATCH + b0 + k];
            wx[i0] = make_float2(s0.x - 2.f*v0.x, s0.y - 2.f*v0.y);
            wx[i1] = make_float2(s1.x - 2.f*v1.x, s1.y - 2.f*v1.y);
        } else if (MODE == 1) {
            tout[i0] = v0; tout[i1] = v1;
            float2 p0 = wx[i0], p1 = wx[i1];
            wx[i0] = make_float2(p0.x + 2.f*v0.x, p0.y + 2.f*v0.y);
            wx[i1] = make_float2(p1.x + 2.f*v1.x, p1.y + 2.f*v1.y);
        } else {
            float2 p0 = wx[i0], p1 = wx[i1];
            wx[i0] = make_float2(p0.x - 2.f*v0.x, p0.y - 2.f*v0.y);
            wx[i1] = make_float2(p1.x - 2.f*v1.x, p1.y - 2.f*v1.y);
        }
    }
}

// ---------------- frequency-domain 1x1 conv: wxh[f,o,b] = sum_c Ht[c][o] wx[f,c,b] ----------------
__global__ __launch_bounds__(256) void h_pass(const float* __restrict__ Ht,
                                              const float2* __restrict__ wx,
                                              float2* __restrict__ wxh, int f0) {
    __shared__ float2 zs[NCH * NBATCH];
    int fl = blockIdx.x >> 2, oq = blockIdx.x & 3;
    int f = f0 + fl;
    const float2* zin = wx + (size_t)f * (NCH * NBATCH);
    for (int m = threadIdx.x; m < NCH * NBATCH; m += 256) zs[m] = zin[m];
    __syncthreads();
    int oi = threadIdx.x & 31, bi = threadIdx.x >> 5;
    int o0 = oq * 64 + oi * 2, b0 = bi * 4;
    const float4* zp = (const float4*)zs;
    float2 acc0[4], acc1[4];
#pragma unroll
    for (int k = 0; k < 4; k++) { acc0[k] = make_float2(0,0); acc1[k] = make_float2(0,0); }
#pragma unroll 4
    for (int c = 0; c < 256; c++) {
        float2 h = *(const float2*)(Ht + (size_t)c * NCH + o0);
        int zb = (c * 32 + b0) >> 1;
        float4 zva = zp[zb], zvb = zp[zb + 1];
        float2 zv[4] = { make_float2(zva.x, zva.y), make_float2(zva.z, zva.w),
                         make_float2(zvb.x, zvb.y), make_float2(zvb.z, zvb.w) };
#pragma unroll
        for (int k = 0; k < 4; k++) {
            acc0[k].x += h.x * zv[k].x; acc0[k].y += h.x * zv[k].y;
            acc1[k].x += h.y * zv[k].x; acc1[k].y += h.y * zv[k].y;
        }
    }
    size_t base = ((size_t)f * NCH + o0) * NBATCH + b0;
#pragma unroll
    for (int k = 0; k < 4; k++) {
        wxh[base + k] = acc0[k];
        wxh[base + NBATCH + k] = acc1[k];
    }
}

// ---------------- pass I: complex ifft along i:  G[j][ob][r] = (1/32) sum_i Y[(i,j)][ob] e^{+i 2pi i r/32} ----------------
__global__ __launch_bounds__(256) void ifft_i(const float2* __restrict__ wxh, float2* __restrict__ G) {
    int j = blockIdx.x >> 5, obc = blockIdx.x & 31;
    int ob = obc * 256 + threadIdx.x;
    __shared__ float2 wt[32];   // e^{+i 2pi m/32}
    if (threadIdx.x < 32) {
        float ph = 2.f * PI_F * (float)threadIdx.x / 32.f;
        wt[threadIdx.x] = make_float2(cosf(ph), sinf(ph));
    }
    __syncthreads();
    float2 Gacc[32];
#pragma unroll
    for (int r = 0; r < 32; r++) Gacc[r] = make_float2(0.f, 0.f);
    for (int i = 0; i < 32; i++) {
        float2 Y = wxh[((size_t)(i * 17 + j)) * 8192 + ob];
        int ir = 0;
#pragma unroll
        for (int r = 0; r < 32; r++) {
            float2 e = wt[ir];
            Gacc[r].x += Y.x*e.x - Y.y*e.y;
            Gacc[r].y += Y.x*e.y + Y.y*e.x;
            ir = (ir + i) & 31;
        }
    }
    float2* gp = G + ((size_t)j * 8192 + ob) * 32;
#pragma unroll
    for (int r = 0; r < 32; r++)
        gp[r] = make_float2(Gacc[r].x * (1.f/32.f), Gacc[r].y * (1.f/32.f));
}

// ---------------- pass II: irfft along j + bias -> out[b][o][r][s] ----------------
__global__ __launch_bounds__(256) void irfft_j(const float2* __restrict__ G,
                                               const float* __restrict__ bias,
                                               float* __restrict__ out) {
    int gid = blockIdx.x * 256 + threadIdx.x;
    int ob = gid >> 5, r = gid & 31;
    int o = ob >> 5, b = ob & 31;
    __shared__ float2 wt[32];   // e^{+i 2pi m/32}
    if (threadIdx.x < 32) {
        float ph = 2.f * PI_F * (float)threadIdx.x / 32.f;
        wt[threadIdx.x] = make_float2(cosf(ph), sinf(ph));
    }
    __syncthreads();
    float2 Gv[17];
#pragma unroll
    for (int j = 0; j < 17; j++) Gv[j] = G[((size_t)j * 8192 + ob) * 32 + r];
    float y[32];
    float g0 = Gv[0].x, g16 = Gv[16].x;
#pragma unroll
    for (int s = 0; s < 32; s++) y[s] = g0 + ((s & 1) ? -g16 : g16);
#pragma unroll
    for (int j = 1; j < 16; j++) {
        int js = 0;
#pragma unroll
        for (int s = 0; s < 32; s++) {
            float2 e = wt[js];
            y[s] += 2.f * (Gv[j].x * e.x - Gv[j].y * e.y);
            js = (js + j) & 31;
        }
    }
    float bv = bias[o];
    float* op = out + ((size_t)(b * NCH + o) * 32 + r) * 32;
#pragma unroll
    for (int s = 0; s < 32; s++) op[s] = y[s] * (1.f/32.f) + bv;
}

extern "C" void kernel_launch(void* const* d_in, const int* in_sizes, int n_in,
                              void* d_out, int out_size, void* d_ws, size_t ws_size,
                              hipStream_t stream) {
    (void)in_sizes; (void)n_in; (void)out_size;
    if (ws_size < WS_NEED) return;   // loud failure (out stays zero) if scratch too small

    const float* x     = (const float*)d_in[0];
    const float* w     = (const float*)d_in[1];
    const float* alpha = (const float*)d_in[2];
    const float* H     = (const float*)d_in[3];
    const float* bias  = (const float*)d_in[4];
    float* out = (float*)d_out;

    char* ws = (char*)d_ws;
    float2* At  = (float2*)(ws + OFF_AT);
    float2* z0  = (float2*)(ws + OFF_Z0);   // also wxh (aliased after H-pass per chunk)
    float2* wx  = (float2*)(ws + OFF_WX);
    float2* tA  = (float2*)(ws + OFF_TA);   // also tmp (FFT tile-major) and G (post-chunks)
    float2* tB  = (float2*)(ws + OFF_TB);
    float*  Ht  = (float*)(ws + OFF_HT);
    float*  red = (float*)(ws + OFF_RED);
    float*  sig = red + 256;

    norm_part<<<256, 256, 0, stream>>>(w, red);
    norm_final<<<1, 256, 0, stream>>>(red, alpha, sig);
    ht_build<<<256, 256, 0, stream>>>(H, Ht);

    rfft2_tile<<<8192, 64, 0, stream>>>(x, tA);                  // tA used as tmp[cb][f]
    transpose_cb_f<<<dim3(256, 17), 256, 0, stream>>>(tA, z0);   // z0[f][c][b]

    for (int k = 0; k < NCHUNK; k++) {
        int f0 = k * FPC;
        a_build<<<256, 256, 0, stream>>>(w, sig, At, f0);
        neumann_k<0><<<FPC * 4, 256, 0, stream>>>(At, z0, tA, wx, f0);
        neumann_k<1><<<FPC * 4, 256, 0, stream>>>(At, tA, tB, wx, f0);
        neumann_k<2><<<FPC * 4, 256, 0, stream>>>(At, tB, nullptr, wx, f0);
        h_pass<<<FPC * 4, 256, 0, stream>>>(Ht, wx, z0, f0);     // wxh aliases z0
    }

    ifft_i<<<544, 256, 0, stream>>>(z0, tA);    // G aliases tA
    irfft_j<<<1024, 256, 0, stream>>>(tA, bias, out);
}

// Round 2
// 351.636 us; speedup vs baseline: 4.8437x; 4.8437x over previous
//
#include <hip/hip_runtime.h>
#include <cstddef>

#define PI_F 3.14159265358979323846f

#define NCH 256   // C
#define NB  32    // B
#define NF  544   // n*(n/2+1)
#define FPC 272   // freqs per A-chunk (2 chunks)

typedef short  bf16x8 __attribute__((ext_vector_type(8)));
typedef float  f32x4  __attribute__((ext_vector_type(4)));

// ---- workspace layout (bytes) ----
#define SZ_AFRAG ((size_t)FPC*8*16*2*1024)      // 71,303,168  (A fragments, chunk-local; G aliases here later)
#define SZ_PLANE ((size_t)NF*NB*NCH*2)          // 8,912,896   (bf16 plane [f][b][c])
#define SZ_P32   ((size_t)NF*NB*NCH*4)          // 17,825,792  (fp32 plane)
#define SZ_WXH   ((size_t)NF*8192*8)            // 35,651,584  (float2 [f][o*32+b]; also tmp)
#define OFF_AFRAG ((size_t)0)
#define OFF_ZBR  (OFF_AFRAG + SZ_AFRAG)         // z bf16 real; later wx real (per-f exact alias, safe)
#define OFF_ZBI  (OFF_ZBR + SZ_PLANE)
#define OFF_TBR  (OFF_ZBI + SZ_PLANE)
#define OFF_TBI  (OFF_TBR + SZ_PLANE)
#define OFF_Z32R (OFF_TBI + SZ_PLANE)
#define OFF_Z32I (OFF_Z32R + SZ_P32)
#define OFF_WXH  (OFF_Z32I + SZ_P32)            // wxh float2; also tmp (rfft2 out, dead after transpose)
#define OFF_HFRAG (OFF_WXH + SZ_WXH)
#define SZ_HFRAG ((size_t)8*16*1024)            // 131,072
#define OFF_RED  (OFF_HFRAG + SZ_HFRAG)
#define WS_NEED  (OFF_RED + (size_t)4096)       // ~178.4 MB (< 214 MB proven available in R1)

__device__ __forceinline__ unsigned short f2bf(float x) {
    unsigned int u = __float_as_uint(x);
    u += 0x7FFFu + ((u >> 16) & 1u);            // RNE
    return (unsigned short)(u >> 16);
}
__device__ __forceinline__ unsigned int pack2(float a, float b) {
    return (unsigned int)f2bf(a) | ((unsigned int)f2bf(b) << 16);
}

// ---------------- norm of wfft (closed form via Parseval) ----------------
__global__ void norm_part(const float* __restrict__ w, float* __restrict__ red) {
    int idx = blockIdx.x * 256 + threadIdx.x;
    const float* wp = w + (size_t)idx * 9;
    float s2 = 0.f, aa = 0.f, bb = 0.f;
#pragma unroll
    for (int u = 0; u < 3; u++) {
        float w0 = wp[u*3+0], w1 = wp[u*3+1], w2 = wp[u*3+2];
        s2 += w0*w0 + w1*w1 + w2*w2;
        float au = w0 + w1 + w2, bu = w0 - w1 + w2;
        aa += au*au; bb += bu*bu;
    }
    float p = 512.f*s2 + 16.f*(aa + bb);
    __shared__ float sm[256];
    sm[threadIdx.x] = p; __syncthreads();
    for (int s = 128; s > 0; s >>= 1) {
        if (threadIdx.x < s) sm[threadIdx.x] += sm[threadIdx.x + s];
        __syncthreads();
    }
    if (threadIdx.x == 0) red[blockIdx.x] = sm[0];
}

__global__ void norm_final(const float* __restrict__ red, const float* __restrict__ alpha,
                           float* __restrict__ sig) {
    __shared__ float sm[256];
    sm[threadIdx.x] = red[threadIdx.x]; __syncthreads();
    for (int s = 128; s > 0; s >>= 1) {
        if (threadIdx.x < s) sm[threadIdx.x] += sm[threadIdx.x + s];
        __syncthreads();
    }
    if (threadIdx.x == 0) sig[0] = alpha[0] / sqrtf(sm[0]);
}

// ---------------- H fragments: Hfrag[kk][mt][lane][8], o=mt*16+(l&15), c=kk*32+(l>>4)*8+e ----------------
__global__ void hfrag_build(const float* __restrict__ H, unsigned short* __restrict__ Hfrag) {
    int kk = blockIdx.x, mt = blockIdx.y, lane = threadIdx.x;   // 64 threads
    int o = mt*16 + (lane & 15), c0 = kk*32 + (lane >> 4)*8;
    const float* hp = H + (size_t)o*NCH + c0;
    uint4 u;
    u.x = pack2(hp[0], hp[1]); u.y = pack2(hp[2], hp[3]);
    u.z = pack2(hp[4], hp[5]); u.w = pack2(hp[6], hp[7]);
    ((uint4*)Hfrag)[((size_t)kk*16 + mt)*64 + lane] = u;
}

// ---------------- rfft2 per (c,b) tile -> tmp[cb][f] ----------------
__global__ void rfft2_tile(const float* __restrict__ x, float2* __restrict__ tmp) {
    int c = blockIdx.x >> 5, b = blockIdx.x & 31;
    __shared__ float  xt[1024];
    __shared__ float2 T[544];
    __shared__ float2 wtab[32];
    int t = threadIdx.x;
    const float* xp = x + ((size_t)(b * NCH + c)) * 1024;
    for (int m = t; m < 1024; m += 64) xt[m] = xp[m];
    if (t < 32) {
        float ph = -2.f * PI_F * (float)t / 32.f;
        wtab[t] = make_float2(cosf(ph), sinf(ph));
    }
    __syncthreads();
    for (int o = t; o < 544; o += 64) {
        int r = o / 17, j = o - r * 17;
        float2 acc = make_float2(0.f, 0.f);
        for (int s = 0; s < 32; s++) {
            float xv = xt[r*32 + s];
            float2 wv = wtab[(j * s) & 31];
            acc.x += xv * wv.x; acc.y += xv * wv.y;
        }
        T[o] = acc;
    }
    __syncthreads();
    float2* op = tmp + (size_t)blockIdx.x * 544;
    for (int o = t; o < 544; o += 64) {
        int i = o / 17, j = o - i * 17;
        float2 acc = make_float2(0.f, 0.f);
        for (int r = 0; r < 32; r++) {
            float2 wv = wtab[(i * r) & 31];
            float2 tv = T[r*17 + j];
            acc.x += wv.x*tv.x - wv.y*tv.y;
            acc.y += wv.x*tv.y + wv.y*tv.x;
        }
        op[o] = acc;
    }
}

// ---------------- transpose tmp[cb][f] -> plane layouts [f][b][c] (fp32 + bf16) ----------------
__global__ __launch_bounds__(256) void transpose_z(const float2* __restrict__ tmp,
        float* __restrict__ z32r, float* __restrict__ z32i,
        unsigned short* __restrict__ zbr, unsigned short* __restrict__ zbi)
{
    __shared__ float2 tile[32][33];
    int ct = blockIdx.x, ft = blockIdx.y, b = blockIdx.z;
    int t = threadIdx.x;
#pragma unroll
    for (int it = 0; it < 4; it++) {
        int idx = t + it*256; int cl = idx >> 5, fl = idx & 31;
        tile[cl][fl] = tmp[((size_t)((ct*32 + cl)*32 + b))*544 + ft*32 + fl];
    }
    __syncthreads();
#pragma unroll
    for (int it = 0; it < 4; it++) {
        int idx = t + it*256; int fl = idx >> 5, cl = idx & 31;
        float2 v = tile[cl][fl];
        size_t zi_ = ((size_t)(ft*32 + fl)*NB + b)*NCH + ct*32 + cl;
        z32r[zi_] = v.x; z32i[zi_] = v.y;
        zbr[zi_] = f2bf(v.x); zbi[zi_] = f2bf(v.y);
    }
}

// ---------------- A-build directly into MFMA fragment order ----------------
// Afrag[fl][kk][mt][plane][lane][8] bf16, 1KB chunks. A[f][c][cp], m=c, k=cp.
__global__ __launch_bounds__(256) void a_build_frag(const float* __restrict__ w,
        const float* __restrict__ sig, unsigned short* __restrict__ Afrag, int f0)
{
    __shared__ float2 wtab[32];
    __shared__ unsigned short lar[512], lai[512];
    int t = threadIdx.x;
    if (t < 32) {
        float ph = -2.f * PI_F * (float)t / 32.f;
        wtab[t] = make_float2(cosf(ph), sinf(ph));
    }
    int mt = blockIdx.x, kk = blockIdx.y, fs = blockIdx.z;
    int c = mt*16 + (t & 15), cpl = t >> 4;
    int cpA = kk*32 + cpl, cpB = cpA + 16;
    float w1a[9], w1b[9], w2a[9], w2b[9];
    const float* pa1 = w + ((size_t)c*NCH + cpA)*9;
    const float* pb1 = w + ((size_t)c*NCH + cpB)*9;
    const float* pa2 = w + ((size_t)cpA*NCH + c)*9;
    const float* pb2 = w + ((size_t)cpB*NCH + c)*9;
#pragma unroll
    for (int q = 0; q < 9; q++) { w1a[q]=pa1[q]; w1b[q]=pb1[q]; w2a[q]=pa2[q]; w2b[q]=pb2[q]; }
    float s = sig[0];
    int la_ = ((c & 15) + 16*(cpl>>3))*8 + (cpl & 7);
    int lb_ = la_ + 32*8;
    __syncthreads();
    for (int fl = fs*68; fl < fs*68 + 68; fl++) {
        int f = f0 + fl;
        int i = f / 17, j = f - i*17;
        int iu[3] = {0, i, (2*i)&31};
        int jv[3] = {0, j, (2*j)&31};
        float2 W1a = {0,0}, W1b = {0,0}, W2a = {0,0}, W2b = {0,0};
#pragma unroll
        for (int u = 0; u < 3; u++) {
#pragma unroll
            for (int v = 0; v < 3; v++) {
                float2 e = wtab[(iu[u] + jv[v]) & 31];
                int q = u*3 + v;
                W1a.x += w1a[q]*e.x; W1a.y += w1a[q]*e.y;
                W1b.x += w1b[q]*e.x; W1b.y += w1b[q]*e.y;
                W2a.x += w2a[q]*e.x; W2a.y += w2a[q]*e.y;
                W2b.x += w2b[q]*e.x; W2b.y += w2b[q]*e.y;
            }
        }
        float2 sf = wtab[(i + j) & 31];
        float arA = s*((sf.x*W1a.x + sf.y*W1a.y) - (sf.x*W2a.x + sf.y*W2a.y));
        float aiA = s*((sf.y*W1a.x - sf.x*W1a.y) - (sf.x*W2a.y - sf.y*W2a.x));
        float arB = s*((sf.x*W1b.x + sf.y*W1b.y) - (sf.x*W2b.x + sf.y*W2b.y));
        float aiB = s*((sf.y*W1b.x - sf.x*W1b.y) - (sf.x*W2b.y - sf.y*W2b.x));
        lar[la_] = f2bf(arA); lai[la_] = f2bf(aiA);
        lar[lb_] = f2bf(arB); lai[lb_] = f2bf(aiB);
        __syncthreads();
        size_t bch = (((size_t)fl*8 + kk)*16 + mt)*256;   // uint2 units
        ((uint2*)Afrag)[bch + t] = (t < 128) ? ((const uint2*)lar)[t]
                                             : ((const uint2*)lai)[t - 128];
        __syncthreads();
    }
}

// ---------------- Neumann pass via MFMA ----------------
// MODE 1: out = z32 - acc   (t = z - A z)
// MODE 2: out = z32 - 2*acc (wx = z - 2 A t)
template<int MODE>
__global__ __launch_bounds__(256) void neum_pass(
    const unsigned short* __restrict__ Afrag,
    const unsigned short* __restrict__ BR, const unsigned short* __restrict__ BI,
    const float* __restrict__ z32r, const float* __restrict__ z32i,
    unsigned short* __restrict__ outR, unsigned short* __restrict__ outI, int f0)
{
    __shared__ uint4 lz[2][1024];   // 32 KB, swizzled [plane][b*32 + (o16^ (b&7))]
    int fl = blockIdx.x >> 1, half = blockIdx.x & 1;
    int f = f0 + fl;
    int t = threadIdx.x;
    const uint4* s0 = (const uint4*)(BR + (size_t)f*8192);
    const uint4* s1 = (const uint4*)(BI + (size_t)f*8192);
    for (int u = t; u < 1024; u += 256) {
        int b = u >> 5, o16 = u & 31;
        int du = b*32 + (o16 ^ (b & 7));
        lz[0][du] = s0[u];
        lz[1][du] = s1[u];
    }
    __syncthreads();
    int w = t >> 6, lane = t & 63, lo = lane & 15, hi = lane >> 4;
    f32x4 accr[2][2], acci[2][2];
    f32x4 zz = {0.f, 0.f, 0.f, 0.f};
#pragma unroll
    for (int mt = 0; mt < 2; mt++)
#pragma unroll
        for (int nt = 0; nt < 2; nt++) { accr[mt][nt] = zz; acci[mt][nt] = zz; }
    const uint4* A4 = (const uint4*)Afrag;
    for (int kk = 0; kk < 8; kk++) {
        bf16x8 ar[2], ai[2], ain[2];
#pragma unroll
        for (int mt = 0; mt < 2; mt++) {
            int mtg = half*8 + w*2 + mt;
            size_t idx = ((((size_t)fl*8 + kk)*16 + mtg)*2)*64 + lane;
            uint4 va = A4[idx], vb = A4[idx + 64];
            ar[mt] = __builtin_bit_cast(bf16x8, va);
            ai[mt] = __builtin_bit_cast(bf16x8, vb);
            uint4 vn = make_uint4(vb.x ^ 0x80008000u, vb.y ^ 0x80008000u,
                                  vb.z ^ 0x80008000u, vb.w ^ 0x80008000u);
            ain[mt] = __builtin_bit_cast(bf16x8, vn);
        }
        bf16x8 zr[2], zi_[2];
#pragma unroll
        for (int nt = 0; nt < 2; nt++) {
            int b = nt*16 + lo;
            int du = b*32 + ((kk*4 + hi) ^ (b & 7));
            zr[nt]  = __builtin_bit_cast(bf16x8, lz[0][du]);
            zi_[nt] = __builtin_bit_cast(bf16x8, lz[1][du]);
        }
#pragma unroll
        for (int mt = 0; mt < 2; mt++)
#pragma unroll
            for (int nt = 0; nt < 2; nt++) {
                accr[mt][nt] = __builtin_amdgcn_mfma_f32_16x16x32_bf16(ar[mt],  zr[nt],  accr[mt][nt], 0, 0, 0);
                accr[mt][nt] = __builtin_amdgcn_mfma_f32_16x16x32_bf16(ain[mt], zi_[nt], accr[mt][nt], 0, 0, 0);
                acci[mt][nt] = __builtin_amdgcn_mfma_f32_16x16x32_bf16(ar[mt],  zi_[nt], acci[mt][nt], 0, 0, 0);
                acci[mt][nt] = __builtin_amdgcn_mfma_f32_16x16x32_bf16(ai[mt],  zr[nt],  acci[mt][nt], 0, 0, 0);
            }
    }
#pragma unroll
    for (int mt = 0; mt < 2; mt++)
#pragma unroll
        for (int nt = 0; nt < 2; nt++) {
            int c0 = half*128 + w*32 + mt*16 + hi*4;
            int b  = nt*16 + lo;
            size_t zb = ((size_t)f*NB + b)*NCH + c0;
            float vr[4], vi[4];
#pragma unroll
            for (int jj = 0; jj < 4; jj++) {
                float zrv = z32r[zb + jj], ziv = z32i[zb + jj];
                float cr = accr[mt][nt][jj], ci = acci[mt][nt][jj];
                if (MODE == 1) { vr[jj] = zrv - cr;      vi[jj] = ziv - ci; }
                else           { vr[jj] = zrv - 2.f*cr;  vi[jj] = ziv - 2.f*ci; }
            }
            uint2 pr = make_uint2(pack2(vr[0], vr[1]), pack2(vr[2], vr[3]));
            uint2 pi = make_uint2(pack2(vi[0], vi[1]), pack2(vi[2], vi[3]));
            *(uint2*)(outR + zb) = pr;
            *(uint2*)(outI + zb) = pi;
        }
}

// ---------------- H pass via MFMA: wxh[f][o][b] = sum_c H[o,c] wx[f,c,b] ----------------
__global__ __launch_bounds__(256) void pass_h(
    const unsigned short* __restrict__ Hfrag,
    const unsigned short* __restrict__ BR, const unsigned short* __restrict__ BI,
    float2* __restrict__ wxh, int f0)
{
    __shared__ uint4 lz[2][1024];
    int fl = blockIdx.x >> 1, half = blockIdx.x & 1;
    int f = f0 + fl;
    int t = threadIdx.x;
    const uint4* s0 = (const uint4*)(BR + (size_t)f*8192);
    const uint4* s1 = (const uint4*)(BI + (size_t)f*8192);
    for (int u = t; u < 1024; u += 256) {
        int b = u >> 5, o16 = u & 31;
        int du = b*32 + (o16 ^ (b & 7));
        lz[0][du] = s0[u];
        lz[1][du] = s1[u];
    }
    __syncthreads();
    int w = t >> 6, lane = t & 63, lo = lane & 15, hi = lane >> 4;
    f32x4 accr[2][2], acci[2][2];
    f32x4 zz = {0.f, 0.f, 0.f, 0.f};
#pragma unroll
    for (int mt = 0; mt < 2; mt++)
#pragma unroll
        for (int nt = 0; nt < 2; nt++) { accr[mt][nt] = zz; acci[mt][nt] = zz; }
    const uint4* H4 = (const uint4*)Hfrag;
    for (int kk = 0; kk < 8; kk++) {
        bf16x8 hm[2];
#pragma unroll
        for (int mt = 0; mt < 2; mt++) {
            int mtg = half*8 + w*2 + mt;
            hm[mt] = __builtin_bit_cast(bf16x8, H4[((size_t)kk*16 + mtg)*64 + lane]);
        }
        bf16x8 zr[2], zi_[2];
#pragma unroll
        for (int nt = 0; nt < 2; nt++) {
            int b = nt*16 + lo;
            int du = b*32 + ((kk*4 + hi) ^ (b & 7));
            zr[nt]  = __builtin_bit_cast(bf16x8, lz[0][du]);
            zi_[nt] = __builtin_bit_cast(bf16x8, lz[1][du]);
        }
#pragma unroll
        for (int mt = 0; mt < 2; mt++)
#pragma unroll
            for (int nt = 0; nt < 2; nt++) {
                accr[mt][nt] = __builtin_amdgcn_mfma_f32_16x16x32_bf16(hm[mt], zr[nt],  accr[mt][nt], 0, 0, 0);
                acci[mt][nt] = __builtin_amdgcn_mfma_f32_16x16x32_bf16(hm[mt], zi_[nt], acci[mt][nt], 0, 0, 0);
            }
    }
#pragma unroll
    for (int mt = 0; mt < 2; mt++)
#pragma unroll
        for (int nt = 0; nt < 2; nt++) {
            int o0 = half*128 + w*32 + mt*16 + hi*4;
            int b  = nt*16 + lo;
#pragma unroll
            for (int jj = 0; jj < 4; jj++) {
                wxh[((size_t)f*NCH + o0 + jj)*NB + b] =
                    make_float2(accr[mt][nt][jj], acci[mt][nt][jj]);
            }
        }
}

// ---------------- pass I: complex ifft along i ----------------
__global__ __launch_bounds__(256) void ifft_i(const float2* __restrict__ wxh, float2* __restrict__ G) {
    int j = blockIdx.x >> 5, obc = blockIdx.x & 31;
    int ob = obc * 256 + threadIdx.x;
    __shared__ float2 wt[32];
    if (threadIdx.x < 32) {
        float ph = 2.f * PI_F * (float)threadIdx.x / 32.f;
        wt[threadIdx.x] = make_float2(cosf(ph), sinf(ph));
    }
    __syncthreads();
    float2 Gacc[32];
#pragma unroll
    for (int r = 0; r < 32; r++) Gacc[r] = make_float2(0.f, 0.f);
    for (int i = 0; i < 32; i++) {
        float2 Y = wxh[((size_t)(i * 17 + j)) * 8192 + ob];
        int ir = 0;
#pragma unroll
        for (int r = 0; r < 32; r++) {
            float2 e = wt[ir];
            Gacc[r].x += Y.x*e.x - Y.y*e.y;
            Gacc[r].y += Y.x*e.y + Y.y*e.x;
            ir = (ir + i) & 31;
        }
    }
    float2* gp = G + ((size_t)j * 8192 + ob) * 32;
#pragma unroll
    for (int r = 0; r < 32; r++)
        gp[r] = make_float2(Gacc[r].x * (1.f/32.f), Gacc[r].y * (1.f/32.f));
}

// ---------------- pass II: irfft along j + bias -> out[b][o][r][s] ----------------
__global__ __launch_bounds__(256) void irfft_j(const float2* __restrict__ G,
                                               const float* __restrict__ bias,
                                               float* __restrict__ out) {
    int gid = blockIdx.x * 256 + threadIdx.x;
    int ob = gid >> 5, r = gid & 31;
    int o = ob >> 5, b = ob & 31;
    __shared__ float2 wt[32];
    if (threadIdx.x < 32) {
        float ph = 2.f * PI_F * (float)threadIdx.x / 32.f;
        wt[threadIdx.x] = make_float2(cosf(ph), sinf(ph));
    }
    __syncthreads();
    float2 Gv[17];
#pragma unroll
    for (int j = 0; j < 17; j++) Gv[j] = G[((size_t)j * 8192 + ob) * 32 + r];
    float y[32];
    float g0 = Gv[0].x, g16 = Gv[16].x;
#pragma unroll
    for (int s = 0; s < 32; s++) y[s] = g0 + ((s & 1) ? -g16 : g16);
#pragma unroll
    for (int j = 1; j < 16; j++) {
        int js = 0;
#pragma unroll
        for (int s = 0; s < 32; s++) {
            float2 e = wt[js];
            y[s] += 2.f * (Gv[j].x * e.x - Gv[j].y * e.y);
            js = (js + j) & 31;
        }
    }
    float bv = bias[o];
    float* op = out + ((size_t)(b * NCH + o) * 32 + r) * 32;
#pragma unroll
    for (int s = 0; s < 32; s++) op[s] = y[s] * (1.f/32.f) + bv;
}

extern "C" void kernel_launch(void* const* d_in, const int* in_sizes, int n_in,
                              void* d_out, int out_size, void* d_ws, size_t ws_size,
                              hipStream_t stream) {
    (void)in_sizes; (void)n_in; (void)out_size;
    if (ws_size < WS_NEED) return;

    const float* x     = (const float*)d_in[0];
    const float* w     = (const float*)d_in[1];
    const float* alpha = (const float*)d_in[2];
    const float* H     = (const float*)d_in[3];
    const float* bias  = (const float*)d_in[4];
    float* out = (float*)d_out;

    char* ws = (char*)d_ws;
    unsigned short* Afrag = (unsigned short*)(ws + OFF_AFRAG);
    unsigned short* zbr   = (unsigned short*)(ws + OFF_ZBR);   // also wx real
    unsigned short* zbi   = (unsigned short*)(ws + OFF_ZBI);   // also wx imag
    unsigned short* tbr   = (unsigned short*)(ws + OFF_TBR);
    unsigned short* tbi   = (unsigned short*)(ws + OFF_TBI);
    float* z32r = (float*)(ws + OFF_Z32R);
    float* z32i = (float*)(ws + OFF_Z32I);
    float2* wxh = (float2*)(ws + OFF_WXH);   // aliases tmp
    float2* tmp = (float2*)(ws + OFF_WXH);
    float2* G   = (float2*)(ws + OFF_AFRAG); // aliases Afrag (dead after passes)
    unsigned short* Hfrag = (unsigned short*)(ws + OFF_HFRAG);
    float* red = (float*)(ws + OFF_RED);
    float* sig = red + 256;

    norm_part<<<256, 256, 0, stream>>>(w, red);
    norm_final<<<1, 256, 0, stream>>>(red, alpha, sig);
    hfrag_build<<<dim3(8, 16), 64, 0, stream>>>(H, Hfrag);

    rfft2_tile<<<8192, 64, 0, stream>>>(x, tmp);
    transpose_z<<<dim3(8, 17, 32), 256, 0, stream>>>(tmp, z32r, z32i, zbr, zbi);

    for (int ch = 0; ch < 2; ch++) {
        int f0 = ch * FPC;
        a_build_frag<<<dim3(16, 8, 4), 256, 0, stream>>>(w, sig, Afrag, f0);
        neum_pass<1><<<FPC*2, 256, 0, stream>>>(Afrag, zbr, zbi, z32r, z32i, tbr, tbi, f0);
        neum_pass<2><<<FPC*2, 256, 0, stream>>>(Afrag, tbr, tbi, z32r, z32i, zbr, zbi, f0);
        pass_h<<<FPC*2, 256, 0, stream>>>(Hfrag, zbr, zbi, wxh, f0);
    }

    ifft_i<<<544, 256, 0, stream>>>(wxh, G);
    irfft_j<<<1024, 256, 0, stream>>>(G, bias, out);
}